// Round 1
// 82.074 us; speedup vs baseline: 1.0327x; 1.0327x over previous
//
#include <hip/hip_runtime.h>

#define NPTS 16384
#define NSPLIT 128
#define CHUNK (NPTS / NSPLIT)        // 128 sources per chunk
#define TPT 8                        // targets per thread
#define TBLK (NPTS / (256 * TPT))    // 8 target blocks

// Kernel 1: per (target-block, source-chunk) partial MIN of d2 = ||s||^2 - 2 t.s.
// No index tracking: loss only needs min distance.
// LDS stages chunk as {-2x, -2y, -2z, ||s||^2}; d2 = 3-FMA chain.
// Sources processed in pairs so clang fuses fminf(fminf(d0,d1),best) -> v_min3_f32:
// 7 VALU ops per 2 sources per target instead of 8.
// Grid 8x128 = 1024 blocks = 4 blocks/CU = 4 waves/SIMD (was 2) to hide ds_read latency.
__global__ __launch_bounds__(256) void nn_min(const float* __restrict__ src,
                                              const float* __restrict__ tar,
                                              float* __restrict__ ws) {
    __shared__ float4 sp[CHUNK];
    const int tid = threadIdx.x;
    const int tb  = blockIdx.x;
    const int sc  = blockIdx.y;
    const int sbase = sc * CHUNK;

    for (int i = tid; i < CHUNK; i += 256) {
        float x = src[(sbase + i) * 3 + 0];
        float y = src[(sbase + i) * 3 + 1];
        float z = src[(sbase + i) * 3 + 2];
        sp[i] = make_float4(-2.0f * x, -2.0f * y, -2.0f * z, x * x + y * y + z * z);
    }
    __syncthreads();

    const int t0 = tb * (256 * TPT) + tid;
    float tx[TPT], ty[TPT], tz[TPT], best[TPT];
#pragma unroll
    for (int k = 0; k < TPT; ++k) {
        const int t = t0 + k * 256;
        tx[k] = tar[t * 3 + 0];
        ty[k] = tar[t * 3 + 1];
        tz[k] = tar[t * 3 + 2];
        best[k] = 1e30f;
    }

#pragma unroll 2
    for (int j = 0; j < CHUNK; j += 2) {
        float4 s0 = sp[j];
        float4 s1 = sp[j + 1];
#pragma unroll
        for (int k = 0; k < TPT; ++k) {
            float d0 = fmaf(tx[k], s0.x, fmaf(ty[k], s0.y, fmaf(tz[k], s0.z, s0.w)));
            float d1 = fmaf(tx[k], s1.x, fmaf(ty[k], s1.y, fmaf(tz[k], s1.z, s1.w)));
            best[k] = fminf(fminf(d0, d1), best[k]);   // -> v_min3_f32
        }
    }
#pragma unroll
    for (int k = 0; k < TPT; ++k)
        ws[sc * NPTS + t0 + k * 256] = best[k];
}

// Kernel 2: reduce NSPLIT partial mins per target, add ||t||^2, sum 0.5*d2 into out.
__global__ __launch_bounds__(256) void nn_sum(const float* __restrict__ tar,
                                              const float* __restrict__ ws,
                                              float* __restrict__ out) {
    const int t = blockIdx.x * 256 + threadIdx.x;
    // 4 independent accumulators for load-latency ILP, min3-fused pairs.
    float b0 = 1e30f, b1 = 1e30f, b2 = 1e30f, b3 = 1e30f;
#pragma unroll 4
    for (int sc = 0; sc < NSPLIT; sc += 8) {
        float v0 = ws[(sc + 0) * NPTS + t];
        float v1 = ws[(sc + 1) * NPTS + t];
        float v2 = ws[(sc + 2) * NPTS + t];
        float v3 = ws[(sc + 3) * NPTS + t];
        float v4 = ws[(sc + 4) * NPTS + t];
        float v5 = ws[(sc + 5) * NPTS + t];
        float v6 = ws[(sc + 6) * NPTS + t];
        float v7 = ws[(sc + 7) * NPTS + t];
        b0 = fminf(fminf(v0, v1), b0);
        b1 = fminf(fminf(v2, v3), b1);
        b2 = fminf(fminf(v4, v5), b2);
        b3 = fminf(fminf(v6, v7), b3);
    }
    float best = fminf(fminf(b0, b1), fminf(b2, b3));
    const float tx = tar[t * 3 + 0], ty = tar[t * 3 + 1], tz = tar[t * 3 + 2];
    float v = 0.5f * (best + tx * tx + ty * ty + tz * tz);   // 0.5*||t-s||^2

    for (int off = 32; off > 0; off >>= 1) v += __shfl_down(v, off, 64);
    __shared__ float wsum[4];
    const int lane = threadIdx.x & 63, wv = threadIdx.x >> 6;
    if (lane == 0) wsum[wv] = v;
    __syncthreads();
    if (threadIdx.x == 0) atomicAdd(out, wsum[0] + wsum[1] + wsum[2] + wsum[3]);
}

// Fallback if d_ws is too small (not expected; ws need == 8 MB):
// single kernel, full source sweep in LDS tiles, min-only.
__global__ __launch_bounds__(256) void nn_all(const float* __restrict__ src,
                                              const float* __restrict__ tar,
                                              float* __restrict__ out) {
    __shared__ float4 sp[2048];
    const int tid = threadIdx.x;
    const int t = blockIdx.x * 256 + tid;
    const float tx = tar[t * 3 + 0], ty = tar[t * 3 + 1], tz = tar[t * 3 + 2];
    float best = 1e30f;
    for (int base = 0; base < NPTS; base += 2048) {
        __syncthreads();
        for (int i = tid; i < 2048; i += 256) {
            float x = src[(base + i) * 3 + 0];
            float y = src[(base + i) * 3 + 1];
            float z = src[(base + i) * 3 + 2];
            sp[i] = make_float4(-2.0f * x, -2.0f * y, -2.0f * z, x * x + y * y + z * z);
        }
        __syncthreads();
#pragma unroll 4
        for (int j = 0; j < 2048; j += 2) {
            float4 s0 = sp[j];
            float4 s1 = sp[j + 1];
            float d0 = fmaf(tx, s0.x, fmaf(ty, s0.y, fmaf(tz, s0.z, s0.w)));
            float d1 = fmaf(tx, s1.x, fmaf(ty, s1.y, fmaf(tz, s1.z, s1.w)));
            best = fminf(fminf(d0, d1), best);
        }
    }
    float v = 0.5f * (best + tx * tx + ty * ty + tz * tz);
    for (int off = 32; off > 0; off >>= 1) v += __shfl_down(v, off, 64);
    __shared__ float wsum[4];
    const int lane = threadIdx.x & 63, wv = threadIdx.x >> 6;
    if (lane == 0) wsum[wv] = v;
    __syncthreads();
    if (threadIdx.x == 0) atomicAdd(out, wsum[0] + wsum[1] + wsum[2] + wsum[3]);
}

extern "C" void kernel_launch(void* const* d_in, const int* in_sizes, int n_in,
                              void* d_out, int out_size, void* d_ws, size_t ws_size,
                              hipStream_t stream) {
    const float* src = (const float*)d_in[0];
    const float* tar = (const float*)d_in[1];
    float* out = (float*)d_out;

    hipMemsetAsync(d_out, 0, sizeof(float) * (size_t)out_size, stream);

    const size_t need = (size_t)NSPLIT * NPTS * sizeof(float);   // 8 MB
    if (ws_size >= need) {
        nn_min<<<dim3(TBLK, NSPLIT), 256, 0, stream>>>(src, tar, (float*)d_ws);
        nn_sum<<<NPTS / 256, 256, 0, stream>>>(tar, (const float*)d_ws, out);
    } else {
        nn_all<<<NPTS / 256, 256, 0, stream>>>(src, tar, out);
    }
}